// Round 2
// baseline (606.414 us; speedup 1.0000x reference)
//
#include <hip/hip_runtime.h>

#define BB   16    // batch
#define NW   32    // WORDS (output capsules)
#define DIMM 256   // DIM
#define DH   32    // DIM_HEAD
#define NI   256   // INNER
#define NJ   256   // J = WORDS*HEADS (input capsules)
#define JP   8     // j's per route/uhat block
#define JG   (NJ / JP)   // 32 j-groups

// xi = x @ Wi^T + bi  -> stored as xh [B, NJ, DH] (identical flat layout)
__global__ void k_proj_in(const float* __restrict__ x, const float* __restrict__ Wi,
                          const float* __restrict__ bi, float* __restrict__ xh) {
    int row = blockIdx.x;          // b*NW + n  (512 rows)
    int k = threadIdx.x;           // 0..255
    __shared__ float xr[DIMM];
    xr[k] = x[(size_t)row * DIMM + k];
    __syncthreads();
    const float4* wi  = (const float4*)(Wi + (size_t)k * DIMM);
    const float4* xr4 = (const float4*)xr;
    float acc = bi[k];
#pragma unroll 8
    for (int m = 0; m < DIMM / 4; ++m) {
        float4 w = wi[m]; float4 xv = xr4[m];
        acc += w.x * xv.x + w.y * xv.y + w.z * xv.z + w.w * xv.w;
    }
    xh[(size_t)row * DIMM + k] = acc;
}

// u[b,j,i,e] = sum_d W[j,i,e,d]*xh[b,j,d] + bias[j,i,e]; also accumulates
// the iter-0 (uniform c) partial sum over this block's 8 j's into part.
// grid: (jg, i) = 32*32 = 1024 blocks; thread = e.
__global__ void k_uhat(const float* __restrict__ W, const float* __restrict__ bias,
                       const float* __restrict__ xh, float* __restrict__ u,
                       float* __restrict__ part) {
    int jg = blockIdx.x >> 5;
    int i  = blockIdx.x & 31;
    int e  = threadIdx.x;
    __shared__ float xs[BB][DH];
    float acc0[BB];
#pragma unroll
    for (int b = 0; b < BB; ++b) acc0[b] = 0.f;

    for (int jj = 0; jj < JP; ++jj) {
        int j = jg * JP + jj;
        __syncthreads();   // protect xs readers from previous iteration
        for (int t = threadIdx.x; t < BB * DH; t += 256) {
            int b = t >> 5, d = t & 31;
            xs[b][d] = xh[((size_t)b * NJ + j) * DH + d];
        }
        __syncthreads();
        const float4* wp = (const float4*)(W + (((size_t)j * NW + i) * NI + e) * DH);
        float4 w4[8];
#pragma unroll
        for (int q = 0; q < 8; ++q) w4[q] = wp[q];
        const float* w = (const float*)w4;
        float bv = bias[((size_t)j * NW + i) * NI + e];
#pragma unroll
        for (int b = 0; b < BB; ++b) {
            float a = bv;
#pragma unroll
            for (int d = 0; d < DH; ++d) a += w[d] * xs[b][d];
            u[(((size_t)b * NJ + j) * NW + i) * NI + e] = a;
            acc0[b] += a;
        }
    }
#pragma unroll
    for (int b = 0; b < BB; ++b)
        part[(((size_t)b * JG + jg) * NW + i) * NI + e] = acc0[b];
}

// One routing iteration over this block's 8 j's:
//   beta[j,i] = dot_e(u[b,j,i,:], v[b,i,:]);  b_log (+)= beta; c = softmax_i;
//   s_partial[i,e] += c[i]*u  (accumulated in registers, written as split-k partial)
// grid: (b, jg) = 512 blocks; thread = e.
__global__ void k_route(const float* __restrict__ u, const float* __restrict__ v,
                        float* __restrict__ b_log, float* __restrict__ part, int accflag) {
    int b  = blockIdx.x / JG;
    int jg = blockIdx.x % JG;
    int tid = threadIdx.x;
    int lane = tid & 63, wave = tid >> 6;
    __shared__ float vs[NW][NI];    // 32 KB
    __shared__ float red[NW][4];
    __shared__ float cs[NW];
    for (int t = tid; t < NW * NI; t += 256)
        vs[t >> 8][t & 255] = v[(size_t)b * NW * NI + t];
    __syncthreads();

    float s_acc[NW];
#pragma unroll
    for (int i = 0; i < NW; ++i) s_acc[i] = 0.f;

    for (int jj = 0; jj < JP; ++jj) {
        int j = jg * JP + jj;
        const float* up = u + ((size_t)b * NJ + j) * NW * NI;
        float ur[NW];
#pragma unroll
        for (int i = 0; i < NW; ++i) ur[i] = up[(size_t)i * NI + tid];
#pragma unroll
        for (int i = 0; i < NW; ++i) {
            float p = ur[i] * vs[i][tid];
#pragma unroll
            for (int off = 32; off >= 1; off >>= 1) p += __shfl_down(p, off);
            if (lane == 0) red[i][wave] = p;
        }
        __syncthreads();
        if (tid < NW) {
            float bta = red[tid][0] + red[tid][1] + red[tid][2] + red[tid][3];
            size_t bidx = ((size_t)b * NJ + j) * NW + tid;
            if (accflag) bta += b_log[bidx];
            b_log[bidx] = bta;
            float m = bta;
#pragma unroll
            for (int mask = 16; mask >= 1; mask >>= 1) m = fmaxf(m, __shfl_xor(m, mask));
            float ex = __expf(bta - m);
            float ssum = ex;
#pragma unroll
            for (int mask = 16; mask >= 1; mask >>= 1) ssum += __shfl_xor(ssum, mask);
            cs[tid] = ex / ssum;
        }
        __syncthreads();
#pragma unroll
        for (int i = 0; i < NW; ++i) s_acc[i] += cs[i] * ur[i];
        // next iteration's red/cs writes are ordered after this read by the
        // __syncthreads() preceding the cs write; red writers are safe (see r1 notes)
    }
#pragma unroll
    for (int i = 0; i < NW; ++i)
        part[(((size_t)b * JG + jg) * NW + i) * NI + tid] = s_acc[i];
}

// s[b,i,e] = scale * sum_g part[b,g,i,e];  v = squash(s)
// grid: (b,i) = 512 blocks; thread = e.
__global__ void k_reduce(const float* __restrict__ part, float* __restrict__ v,
                         float scale) {
    int b = blockIdx.x >> 5;
    int i = blockIdx.x & 31;
    int tid = threadIdx.x;
    int lane = tid & 63, wave = tid >> 6;
    float acc = 0.f;
#pragma unroll 8
    for (int g = 0; g < JG; ++g)
        acc += part[(((size_t)b * JG + g) * NW + i) * NI + tid];
    acc *= scale;
    __shared__ float red[4];
    float p = acc * acc;
#pragma unroll
    for (int off = 32; off >= 1; off >>= 1) p += __shfl_down(p, off);
    if (lane == 0) red[wave] = p;
    __syncthreads();
    float n2 = red[0] + red[1] + red[2] + red[3];
    float n = sqrtf(n2);
    float f = n / (1.0f + n2);
    v[((size_t)b * NW + i) * NI + tid] = f * acc;
}

// out = v @ Wo^T + bo
__global__ void k_proj_out(const float* __restrict__ v, const float* __restrict__ Wo,
                           const float* __restrict__ bo, float* __restrict__ out) {
    int row = blockIdx.x;          // b*NW + i
    int k = threadIdx.x;
    __shared__ float vr[NI];
    vr[k] = v[(size_t)row * NI + k];
    __syncthreads();
    const float4* wo  = (const float4*)(Wo + (size_t)k * NI);
    const float4* vr4 = (const float4*)vr;
    float acc = bo[k];
#pragma unroll 8
    for (int m = 0; m < NI / 4; ++m) {
        float4 w = wo[m]; float4 xv = vr4[m];
        acc += w.x * xv.x + w.y * xv.y + w.z * xv.z + w.w * xv.w;
    }
    out[(size_t)row * DIMM + k] = acc;
}

extern "C" void kernel_launch(void* const* d_in, const int* in_sizes, int n_in,
                              void* d_out, int out_size, void* d_ws, size_t ws_size,
                              hipStream_t stream) {
    const float* x    = (const float*)d_in[0];
    const float* W    = (const float*)d_in[1];
    const float* bias = (const float*)d_in[2];
    const float* Wi   = (const float*)d_in[3];
    const float* bi   = (const float*)d_in[4];
    const float* Wo   = (const float*)d_in[5];
    const float* bo   = (const float*)d_in[6];
    float* out = (float*)d_out;

    float* ws    = (float*)d_ws;
    float* xh    = ws;                      // 131072 floats
    float* u     = ws + 131072;             // 33554432 floats (134 MB)
    float* part  = u + 33554432;            // 4194304 floats (16 MB)
    float* b_log = part + 4194304;          // 131072
    float* v     = b_log + 131072;          // 131072

    k_proj_in<<<dim3(BB * NW), dim3(256), 0, stream>>>(x, Wi, bi, xh);
    // u_hat + iter-0 uniform partial sums
    k_uhat<<<dim3(JG * NW), dim3(256), 0, stream>>>(W, bias, xh, u, part);
    k_reduce<<<dim3(BB * NW), dim3(256), 0, stream>>>(part, v, 1.0f / NW);  // v0
    // iter 1
    k_route<<<dim3(BB * JG), dim3(256), 0, stream>>>(u, v, b_log, part, 0);
    k_reduce<<<dim3(BB * NW), dim3(256), 0, stream>>>(part, v, 1.0f);       // v1
    // iter 2
    k_route<<<dim3(BB * JG), dim3(256), 0, stream>>>(u, v, b_log, part, 1);
    k_reduce<<<dim3(BB * NW), dim3(256), 0, stream>>>(part, v, 1.0f);       // v2
    k_proj_out<<<dim3(BB * NW), dim3(256), 0, stream>>>(v, Wo, bo, out);
}

// Round 3
// 579.807 us; speedup vs baseline: 1.0459x; 1.0459x over previous
//
#include <hip/hip_runtime.h>

#define BB   16    // batch
#define NW   32    // WORDS (output capsules)
#define DIMM 256   // DIM
#define DH   32    // DIM_HEAD
#define NI   256   // INNER
#define NJ   256   // J = WORDS*HEADS (input capsules)
#define JP   4     // j's per route/uhat block
#define JG   (NJ / JP)   // 64 j-groups

// xi = x @ Wi^T + bi  -> stored as xh [B, NJ, DH] (identical flat layout)
__global__ void k_proj_in(const float* __restrict__ x, const float* __restrict__ Wi,
                          const float* __restrict__ bi, float* __restrict__ xh) {
    int row = blockIdx.x;          // b*NW + n  (512 rows)
    int k = threadIdx.x;           // 0..255
    __shared__ float xr[DIMM];
    xr[k] = x[(size_t)row * DIMM + k];
    __syncthreads();
    const float4* wi  = (const float4*)(Wi + (size_t)k * DIMM);
    const float4* xr4 = (const float4*)xr;
    float acc = bi[k];
#pragma unroll 8
    for (int m = 0; m < DIMM / 4; ++m) {
        float4 w = wi[m]; float4 xv = xr4[m];
        acc += w.x * xv.x + w.y * xv.y + w.z * xv.z + w.w * xv.w;
    }
    xh[(size_t)row * DIMM + k] = acc;
}

// u[b,j,i,e] = sum_d W[j,i,e,d]*xh[b,j,d] + bias[j,i,e]; also accumulates
// the iter-0 (uniform c) partial sum over this block's JP j's into part.
// grid: (jg, i) = 64*32 = 2048 blocks; thread = e.
__global__ void k_uhat(const float* __restrict__ W, const float* __restrict__ bias,
                       const float* __restrict__ xh, float* __restrict__ u,
                       float* __restrict__ part) {
    int jg = blockIdx.x >> 5;
    int i  = blockIdx.x & 31;
    int e  = threadIdx.x;
    __shared__ float xs[BB][DH];
    float acc0[BB];
#pragma unroll
    for (int b = 0; b < BB; ++b) acc0[b] = 0.f;

    for (int jj = 0; jj < JP; ++jj) {
        int j = jg * JP + jj;
        __syncthreads();   // protect xs readers from previous iteration
        for (int t = threadIdx.x; t < BB * DH; t += 256) {
            int b = t >> 5, d = t & 31;
            xs[b][d] = xh[((size_t)b * NJ + j) * DH + d];
        }
        __syncthreads();
        const float4* wp = (const float4*)(W + (((size_t)j * NW + i) * NI + e) * DH);
        float4 w4[8];
#pragma unroll
        for (int q = 0; q < 8; ++q) w4[q] = wp[q];
        const float* w = (const float*)w4;
        float bv = bias[((size_t)j * NW + i) * NI + e];
#pragma unroll
        for (int b = 0; b < BB; ++b) {
            float a = bv;
#pragma unroll
            for (int d = 0; d < DH; ++d) a += w[d] * xs[b][d];
            u[(((size_t)b * NJ + j) * NW + i) * NI + e] = a;
            acc0[b] += a;
        }
    }
#pragma unroll
    for (int b = 0; b < BB; ++b)
        part[(((size_t)b * JG + jg) * NW + i) * NI + e] = acc0[b];
}

// One routing iteration over this block's JP j's.
// Thread mapping: t -> i = t>>3 (0..31), h = t&7, e-slice = h*32 .. h*32+31.
// Per j: per-thread 32-FMA partial dot, 3-step shfl_xor over the 8-lane group,
// beta row through LDS, per-thread serial softmax, accumulate c*u in regs.
// grid: (b, jg) = 16*64 = 1024 blocks; 256 threads.
__global__ void k_route(const float* __restrict__ u, const float* __restrict__ v,
                        float* __restrict__ b_log, float* __restrict__ part, int accflag) {
    int b  = blockIdx.x / JG;
    int jg = blockIdx.x % JG;
    int t  = threadIdx.x;
    int i  = t >> 3;
    int h  = t & 7;
    __shared__ float sh_beta[JP][NW];

    // v fragment in registers: v[b, i, h*32 .. h*32+31]
    float vr[32];
    {
        const float4* vp = (const float4*)(v + ((size_t)b * NW + i) * NI + h * 32);
#pragma unroll
        for (int q = 0; q < 8; ++q) ((float4*)vr)[q] = vp[q];
    }
    float s_acc[32];
#pragma unroll
    for (int k = 0; k < 32; ++k) s_acc[k] = 0.f;

    for (int jj = 0; jj < JP; ++jj) {
        int j = jg * JP + jj;
        // load u fragment: u[b, j, i, h*32 ..]
        float ur[32];
        {
            const float4* up = (const float4*)(u + (((size_t)b * NJ + j) * NW + i) * NI + h * 32);
#pragma unroll
            for (int q = 0; q < 8; ++q) ((float4*)ur)[q] = up[q];
        }
        // partial dot u.v over this thread's 32 e's
        float p = 0.f;
#pragma unroll
        for (int k = 0; k < 32; ++k) p += ur[k] * vr[k];
        // reduce across the 8 lanes sharing i
        p += __shfl_xor(p, 1);
        p += __shfl_xor(p, 2);
        p += __shfl_xor(p, 4);
        if (h == 0) {
            size_t bidx = ((size_t)b * NJ + j) * NW + i;
            float bta = p;
            if (accflag) bta += b_log[bidx];
            b_log[bidx] = bta;
            sh_beta[jj][i] = bta;
        }
        __syncthreads();
        // per-thread serial softmax over i (32 broadcast LDS reads)
        float row[NW];
#pragma unroll
        for (int k = 0; k < NW; ++k) row[k] = sh_beta[jj][k];
        float m = row[0];
#pragma unroll
        for (int k = 1; k < NW; ++k) m = fmaxf(m, row[k]);
        float ssum = 0.f;
#pragma unroll
        for (int k = 0; k < NW; ++k) ssum += __expf(row[k] - m);
        float c = __expf(row[i] - m) / ssum;
        // accumulate weighted sum
#pragma unroll
        for (int k = 0; k < 32; ++k) s_acc[k] += c * ur[k];
    }
    // write split-k partial: part[b, jg, i, h*32 ..]
    float4* pp = (float4*)(part + (((size_t)b * JG + jg) * NW + i) * NI + h * 32);
#pragma unroll
    for (int q = 0; q < 8; ++q) pp[q] = ((float4*)s_acc)[q];
}

// s[b,i,e] = scale * sum_g part[b,g,i,e];  v = squash(s)
// grid: (b,i) = 512 blocks; thread = e.
__global__ void k_reduce(const float* __restrict__ part, float* __restrict__ v,
                         float scale) {
    int b = blockIdx.x >> 5;
    int i = blockIdx.x & 31;
    int tid = threadIdx.x;
    int lane = tid & 63, wave = tid >> 6;
    float acc = 0.f;
#pragma unroll 8
    for (int g = 0; g < JG; ++g)
        acc += part[(((size_t)b * JG + g) * NW + i) * NI + tid];
    acc *= scale;
    __shared__ float red[4];
    float p = acc * acc;
#pragma unroll
    for (int off = 32; off >= 1; off >>= 1) p += __shfl_down(p, off);
    if (lane == 0) red[wave] = p;
    __syncthreads();
    float n2 = red[0] + red[1] + red[2] + red[3];
    float n = sqrtf(n2);
    float f = n / (1.0f + n2);
    v[((size_t)b * NW + i) * NI + tid] = f * acc;
}

// out = v @ Wo^T + bo
__global__ void k_proj_out(const float* __restrict__ v, const float* __restrict__ Wo,
                           const float* __restrict__ bo, float* __restrict__ out) {
    int row = blockIdx.x;          // b*NW + i
    int k = threadIdx.x;
    __shared__ float vr[NI];
    vr[k] = v[(size_t)row * NI + k];
    __syncthreads();
    const float4* wo  = (const float4*)(Wo + (size_t)k * NI);
    const float4* vr4 = (const float4*)vr;
    float acc = bo[k];
#pragma unroll 8
    for (int m = 0; m < NI / 4; ++m) {
        float4 w = wo[m]; float4 xv = vr4[m];
        acc += w.x * xv.x + w.y * xv.y + w.z * xv.z + w.w * xv.w;
    }
    out[(size_t)row * DIMM + k] = acc;
}

extern "C" void kernel_launch(void* const* d_in, const int* in_sizes, int n_in,
                              void* d_out, int out_size, void* d_ws, size_t ws_size,
                              hipStream_t stream) {
    const float* x    = (const float*)d_in[0];
    const float* W    = (const float*)d_in[1];
    const float* bias = (const float*)d_in[2];
    const float* Wi   = (const float*)d_in[3];
    const float* bi   = (const float*)d_in[4];
    const float* Wo   = (const float*)d_in[5];
    const float* bo   = (const float*)d_in[6];
    float* out = (float*)d_out;

    float* ws    = (float*)d_ws;
    float* xh    = ws;                      // 131072 floats
    float* u     = ws + 131072;             // 33554432 floats (134 MB)
    float* part  = u + 33554432;            // 8388608 floats (32 MB)
    float* b_log = part + 8388608;          // 131072
    float* v     = b_log + 131072;          // 131072

    k_proj_in<<<dim3(BB * NW), dim3(256), 0, stream>>>(x, Wi, bi, xh);
    // u_hat + iter-0 uniform partial sums
    k_uhat<<<dim3(JG * NW), dim3(256), 0, stream>>>(W, bias, xh, u, part);
    k_reduce<<<dim3(BB * NW), dim3(256), 0, stream>>>(part, v, 1.0f / NW);  // v0
    // iter 1
    k_route<<<dim3(BB * JG), dim3(256), 0, stream>>>(u, v, b_log, part, 0);
    k_reduce<<<dim3(BB * NW), dim3(256), 0, stream>>>(part, v, 1.0f);       // v1
    // iter 2
    k_route<<<dim3(BB * JG), dim3(256), 0, stream>>>(u, v, b_log, part, 1);
    k_reduce<<<dim3(BB * NW), dim3(256), 0, stream>>>(part, v, 1.0f);       // v2
    k_proj_out<<<dim3(BB * NW), dim3(256), 0, stream>>>(v, Wo, bo, out);
}